// Round 12
// baseline (690.815 us; speedup 1.0000x reference)
//
#include <hip/hip_runtime.h>
#include <stdint.h>

#define AS1 __attribute__((address_space(1)))
#define AS3 __attribute__((address_space(3)))

typedef short v8s  __attribute__((ext_vector_type(8)));
typedef float v4f  __attribute__((ext_vector_type(4)));
typedef float v16f __attribute__((ext_vector_type(16)));

#define C_IN  512
#define C_OUT 512
#define HW    64
#define COEF  9.20711955e-04f   // 1 / (16 * sqrt(9*512))

// E ws: [pu(2)][ocb(16)][ph(32)] chunks of [tap(18)][hi(2)][oc(32)][16B] = 18432 B
// (per-lane fragment order: lane (hi,l31) reads tap*1024 + hi*512B + l31*16B)
#define E_PH_SHORTS 9216
#define E_WS_BYTES  (2u*16u*32u*18432u)               // 18,874,368
// x ws: [n(8)][hp(66)][ph(32)][hi(2)][wp(66)][16B]  (8 ic per 16B unit)
#define XT_BYTES    ((size_t)8*66*66*512*2)           // 35,684,352
#define WS_NEED     ((size_t)E_WS_BYTES + XT_BYTES)

// LDS: two ping-pong x buffers [18 rows][2 hi][34 cols]x16B = 19584 B each
#define HALF      19584
#define LDS_BYTES 39168

__device__ __forceinline__ float Gf(int i) {
    return (i < 0 || i > 3) ? 0.f : ((i == 1 || i == 2) ? 3.f : 1.f);
}
__device__ __forceinline__ short f2bf(float f) {
    uint32_t u = __float_as_uint(f);
    u += 0x7fffu + ((u >> 16) & 1u);
    return (short)(u >> 16);
}

// ---------------- precompute: x -> [n][hp][ph][hi][wp] bf16 via LDS transpose ---
__global__ __launch_bounds__(256) void xpose_kernel(const float* __restrict__ x,
                                                    short* __restrict__ xt) {
    const int b     = blockIdx.x;
    const int icb64 = b & 7;
    const int hp    = (b >> 3) % 66;
    const int n     = (b >> 3) / 66;
    const int t     = threadIdx.x;

    __shared__ short tile[64][80];   // [w][ic_local]

    const bool hvalid = (hp >= 1 && hp <= 64);
    if (hvalid) {
        #pragma unroll
        for (int r = 0; r < 4; ++r) {
            const int i  = (t >> 4) + r * 16;     // ic_local 0..63
            const int w0 = (t & 15) * 4;          // w 0..63
            const float* src = x + ((size_t)(n * C_IN + icb64 * 64 + i) * HW + (hp - 1)) * HW + w0;
            float4 v = *(const float4*)src;
            tile[w0 + 0][i] = f2bf(v.x);
            tile[w0 + 1][i] = f2bf(v.y);
            tile[w0 + 2][i] = f2bf(v.z);
            tile[w0 + 3][i] = f2bf(v.w);
        }
    }
    __syncthreads();

    // 66 wp x (4 lph x 2 hi) = 528 units of 16B
    for (int u = t; u < 528; u += 256) {
        const int wp  = u >> 3;
        const int gs  = u & 7;
        const int lph = gs >> 1;
        const int hi  = gs & 1;
        v8s o = (v8s)0;
        if (hvalid && wp >= 1 && wp <= 64)
            o = *(const v8s*)&tile[wp - 1][lph * 16 + hi * 8];
        const int ph = icb64 * 4 + lph;
        *(v8s*)(xt + ((((size_t)(n * 66 + hp) * 32 + ph) * 2 + hi) * 66 + wp) * 8) = o;
    }
}

// ---------------- precompute: E image [tap][hi][oc] per phase chunk -------------
__global__ __launch_bounds__(256) void prep_e_kernel(const float* __restrict__ w,
                                                     short* __restrict__ ews) {
    int u = blockIdx.x * 256 + threadIdx.x;   // 1,179,648 units of 16B
    int oc_l = u & 31;
    int hi   = (u >> 5) & 1;
    int tap  = (u >> 6) % 18;
    int rest = (u >> 6) / 18;                  // ph + 32*(ocb + 16*pu)
    int ph   = rest & 31;
    int ocb  = (rest >> 5) & 15;
    int pu   = rest >> 9;
    int pv   = tap & 1;
    int ts   = tap >> 1;
    int tt   = ts / 3, ss = ts - tt * 3;
    int m    = 2 * tt + 1 - pu;
    int nn   = 2 * ss + 1 - pv;
    int ic0  = ph * 16 + hi * 8;
    int oc   = ocb * 32 + oc_l;

    v8s o;
    #pragma unroll
    for (int j = 0; j < 8; ++j) {
        float acc = 0.f;
        #pragma unroll
        for (int p = 0; p < 3; ++p) {
            float gm = Gf(m - p);
            if (gm != 0.f) {
                #pragma unroll
                for (int q = 0; q < 3; ++q) {
                    float gn = Gf(nn - q);
                    if (gn != 0.f)
                        acc += gm * gn * w[((size_t)(p * 3 + q) * C_IN + ic0 + j) * C_OUT + oc];
                }
            }
        }
        o[j] = f2bf(acc * COEF);
    }
    *(v8s*)(ews + (size_t)u * 8) = o;
}

// ---------------- main MFMA kernel (32x32x16, A via LDS, B from global) ---------
__global__ __launch_bounds__(256, 2) void conv_mfma_kernel(const short* __restrict__ xt,
                                                           const short* __restrict__ ews,
                                                           float* __restrict__ out) {
    int bid  = blockIdx.x;
    int wgid = (bid & 7) * 256 + (bid >> 3);   // bijective XCD swizzle (2048 % 8 == 0)
    int vhb = wgid & 1;  wgid >>= 1;
    int uhb = wgid & 3;  wgid >>= 2;
    int n   = wgid & 7;  wgid >>= 3;
    int ocb = wgid & 15; wgid >>= 4;
    int pu  = wgid;
    const int uh0 = uhb * 16, vh0 = vhb * 32;

    __shared__ char lds_raw[LDS_BYTES];
    AS3 char* lds3 = (AS3 char*)lds_raw;

    const int tid  = threadIdx.x;
    const int lane = tid & 63;
    const int wid  = tid >> 6;      // wave's uh-quarter (0..3)
    const int l31  = lane & 31;
    const int hi   = lane >> 5;

    // B fragment base (per-lane, global): wave-load = contiguous 1KB, L1-shared
    const short* eb = ews + (size_t)((pu * 16 + ocb) * 32) * E_PH_SHORTS
                          + hi * 256 + l31 * 8;
    // x stage source base: rows stride 33792 shorts; within phase: hi*528 + wp*8
    const short* xbase = xt + (size_t)(n * 66 + uh0) * 33792 + vh0 * 8;
    // x units: j in [0,1224): j = row*68 + hi*34 + col  (row 0..17, col 0..33)
    int xoff[5], xdst[5];
    #pragma unroll
    for (int k = 0; k < 5; ++k) {
        int j = k * 256 + tid;
        if (j >= 1224) j = 0;
        const int r   = j / 68;
        const int rr  = j - r * 68;
        const int h_  = rr / 34;
        const int c_  = rr - h_ * 34;
        xoff[k] = r * 33792 + h_ * 528 + c_ * 8;
        xdst[k] = j * 16;
    }

#define STAGE(bufoff, ph_) do {                                                       \
    const short* xp_ = xbase + (size_t)(ph_) * 1056;                                  \
    _Pragma("unroll")                                                                 \
    for (int k_ = 0; k_ < 4; ++k_)                                                    \
        __builtin_amdgcn_global_load_lds((const AS1 void*)(xp_ + xoff[k_]),           \
            (AS3 void*)(lds3 + (bufoff) + xdst[k_]), 16, 0, 0);                       \
    if (tid < 200)                                                                    \
        __builtin_amdgcn_global_load_lds((const AS1 void*)(xp_ + xoff[4]),            \
            (AS3 void*)(lds3 + (bufoff) + xdst[4]), 16, 0, 0);                        \
} while (0)

    v16f acc[4][2];   // [u][pv]
    #pragma unroll
    for (int u = 0; u < 4; ++u)
        #pragma unroll
        for (int pv = 0; pv < 2; ++pv)
            acc[u][pv] = (v16f)0.f;

#define COMPUTE(bufoff, ph_) do {                                                     \
    const short* ep_ = eb + (size_t)(ph_) * E_PH_SHORTS;                              \
    _Pragma("unroll")                                                                 \
    for (int s_ = 0; s_ < 3; ++s_) {                                                  \
        const int c_ = l31 + s_;                                                      \
        v8s A_[6];                                                                    \
        _Pragma("unroll")                                                             \
        for (int rr_ = 0; rr_ < 6; ++rr_)                                             \
            A_[rr_] = *(const v8s*)(lds_raw + (bufoff)                                \
                     + (((wid * 4 + rr_) * 2 + hi) * 34 + c_) * 16);                  \
        _Pragma("unroll")                                                             \
        for (int t_ = 0; t_ < 3; ++t_) {                                              \
            _Pragma("unroll")                                                         \
            for (int pv_ = 0; pv_ < 2; ++pv_) {                                       \
                const int tap_ = (t_ * 3 + s_) * 2 + pv_;                             \
                v8s B_ = *(const v8s*)(ep_ + tap_ * 512);                             \
                _Pragma("unroll")                                                     \
                for (int u_ = 0; u_ < 4; ++u_)                                        \
                    acc[u_][pv_] = __builtin_amdgcn_mfma_f32_32x32x16_bf16(           \
                                       A_[u_ + t_], B_, acc[u_][pv_], 0, 0, 0);       \
            }                                                                         \
        }                                                                             \
    }                                                                                 \
} while (0)

    // ---- prologue + double-buffered main loop: one barrier per 16-ic phase ----
    STAGE(0, 0);
    __syncthreads();                       // drain: phase 0 resident
    #pragma unroll 1
    for (int ph = 0; ph < 32; ++ph) {
        const int boff = (ph & 1) ? HALF : 0;
        const int noff = (ph & 1) ? 0 : HALF;
        if (ph < 31) STAGE(noff, ph + 1);  // issue next-phase x loads FIRST
        COMPUTE(boff, ph);                 // A from LDS, B from global (L1-shared)
        __syncthreads();                   // vmcnt(0)+lgkmcnt(0) drain + barrier
    }
#undef STAGE
#undef COMPUTE

    // epilogue: D col = lane&31 (oc), row = (reg&3) + 8*(reg>>2) + 4*(lane>>5) (vh)
    const int oc_g = ocb * 32 + l31;
    float* ob = out + ((size_t)(n * C_OUT + oc_g)) * 128 * 128;
    #pragma unroll
    for (int u = 0; u < 4; ++u) {
        const int h = 2 * (uh0 + wid * 4 + u) + pu;
        #pragma unroll
        for (int rg = 0; rg < 8; ++rg) {
            const int reg  = rg * 2;
            const int vh_l = (reg & 3) + 8 * (reg >> 2) + 4 * hi;
            v4f f;
            f[0] = acc[u][0][reg];
            f[1] = acc[u][1][reg];
            f[2] = acc[u][0][reg + 1];
            f[3] = acc[u][1][reg + 1];
            *(v4f*)(ob + (size_t)h * 128 + 2 * (vh0 + vh_l)) = f;
        }
    }
}

// ---------------- fallback (validated round-1 VALU kernel) ----------------------
#define ICB 8
#define UB  4
__global__ __launch_bounds__(256) void conv_par_kernel(
        const float* __restrict__ x, const float* __restrict__ w,
        float* __restrict__ out) {
    const int octile = blockIdx.x;
    const int n      = blockIdx.y >> 4;
    const int uhb    = blockIdx.y & 15;
    const int pu     = blockIdx.z >> 1;
    const int pv     = blockIdx.z & 1;
    const int t    = threadIdx.x;
    const int lane = t & 63;
    const int wg   = t >> 6;
    const int ocb  = octile * 64;
    const int uh0  = uhb * UB;
    __shared__ float xs[ICB][6][66];
    __shared__ float esw[9][ICB][64];
    float acc[UB][16];
    #pragma unroll
    for (int u = 0; u < UB; ++u)
        #pragma unroll
        for (int i = 0; i < 16; ++i) acc[u][i] = 0.f;
    for (int icb = 0; icb < C_IN; icb += ICB) {
        __syncthreads();
        for (int e = t; e < ICB * 6 * 66; e += 256) {
            int col = e % 66; int tmp = e / 66; int row = tmp % 6; int ic = tmp / 6;
            int h = uh0 - 1 + row; int ww = col - 1;
            float v = 0.f;
            if (h >= 0 && h < HW && ww >= 0 && ww < HW)
                v = x[((n * C_IN + icb + ic) * HW + h) * HW + ww];
            xs[ic][row][col] = v;
        }
        for (int e = t; e < 9 * ICB * 64; e += 256) {
            int oc = e & 63; int ic = (e >> 6) & (ICB - 1); int pq = e >> 9;
            esw[pq][ic][oc] = w[(pq * C_IN + icb + ic) * C_OUT + ocb + oc];
        }
        __syncthreads();
        float ereg[18];
        #pragma unroll
        for (int j = 0; j < 18; ++j) {
            int e = t + j * 256; int oc = e & 63; int ic = (e >> 6) & (ICB - 1);
            int tap = e >> 9; int t3 = tap / 3, s3 = tap - t3 * 3;
            int m = 2 * t3 + 1 - pu; int nn = 2 * s3 + 1 - pv;
            float gm0 = Gf(m), gm1 = Gf(m - 1), gm2 = Gf(m - 2);
            float gn0 = Gf(nn), gn1 = Gf(nn - 1), gn2 = Gf(nn - 2);
            float s =
              gm0 * (gn0 * esw[0][ic][oc] + gn1 * esw[1][ic][oc] + gn2 * esw[2][ic][oc])
            + gm1 * (gn0 * esw[3][ic][oc] + gn1 * esw[4][ic][oc] + gn2 * esw[5][ic][oc])
            + gm2 * (gn0 * esw[6][ic][oc] + gn1 * esw[7][ic][oc] + gn2 * esw[8][ic][oc]);
            ereg[j] = s * COEF;
        }
        __syncthreads();
        #pragma unroll
        for (int j = 0; j < 18; ++j) {
            int e = t + j * 256; int oc = e & 63; int ic = (e >> 6) & (ICB - 1);
            int tap = e >> 9;
            esw[tap][ic][oc] = ereg[j];
        }
        __syncthreads();
        for (int ic = 0; ic < ICB; ++ic) {
            #pragma unroll
            for (int t3 = 0; t3 < 3; ++t3) {
                #pragma unroll
                for (int s3 = 0; s3 < 3; ++s3) {
                    const int tap = t3 * 3 + s3;
                    float ev[16];
                    #pragma unroll
                    for (int r = 0; r < 4; ++r)
                        *(float4*)&ev[r * 4] = *(const float4*)&esw[tap][ic][wg * 16 + r * 4];
                    float xv[UB];
                    #pragma unroll
                    for (int u = 0; u < UB; ++u) xv[u] = xs[ic][u + t3][lane + s3];
                    #pragma unroll
                    for (int u = 0; u < UB; ++u)
                        #pragma unroll
                        for (int i = 0; i < 16; ++i) acc[u][i] += xv[u] * ev[i];
                }
            }
        }
    }
    #pragma unroll
    for (int u = 0; u < UB; ++u) {
        int urow = 2 * (uh0 + u) + pu;
        #pragma unroll
        for (int i = 0; i < 16; ++i) {
            int oc = ocb + wg * 16 + i;
            out[((n * C_OUT + oc) * 128 + urow) * 128 + 2 * lane + pv] = acc[u][i];
        }
    }
}

extern "C" void kernel_launch(void* const* d_in, const int* in_sizes, int n_in,
                              void* d_out, int out_size, void* d_ws, size_t ws_size,
                              hipStream_t stream) {
    const float* x = (const float*)d_in[0];   // (8,512,64,64) fp32
    const float* w = (const float*)d_in[1];   // (3,3,512,512) fp32 HWIO
    float* out = (float*)d_out;               // (8,512,128,128) fp32

    if (ws_size >= WS_NEED) {
        short* ews = (short*)d_ws;
        short* xtp = (short*)((char*)d_ws + E_WS_BYTES);
        prep_e_kernel<<<4608, 256, 0, stream>>>(w, ews);
        xpose_kernel<<<4224, 256, 0, stream>>>(x, xtp);
        conv_mfma_kernel<<<2048, 256, 0, stream>>>(xtp, ews, out);
    } else {
        dim3 grid(8, 128, 4);
        conv_par_kernel<<<grid, 256, 0, stream>>>(x, w, out);
    }
}

// Round 13
// 520.532 us; speedup vs baseline: 1.3271x; 1.3271x over previous
//
#include <hip/hip_runtime.h>
#include <stdint.h>

#define AS1 __attribute__((address_space(1)))
#define AS3 __attribute__((address_space(3)))

typedef short v8s  __attribute__((ext_vector_type(8)));
typedef float v4f  __attribute__((ext_vector_type(4)));
typedef float v8f  __attribute__((ext_vector_type(8)));
typedef float v16f __attribute__((ext_vector_type(16)));

#define C_IN  512
#define C_OUT 512
#define HW    64
#define COEF  9.20711955e-04f   // 1 / (16 * sqrt(9*512))

// E ws: [pu(2)][ocb(16)][ph(32)] chunks of [tap(18)][hi(2)][oc(32)][16B] = 18432 B
#define E_PH_SHORTS 9216
#define E_WS_BYTES  (2u*16u*32u*18432u)               // 18,874,368
// x ws: [n(8)][hp(66)][ph(32)][hi(2)][wp(66)][16B]  (8 ic per 16B unit)
#define XT_BYTES    ((size_t)8*66*66*512*2)           // 35,684,352
#define WS_NEED     ((size_t)E_WS_BYTES + XT_BYTES)

// LDS: two ping-pong buffers of { E [18][2][32]x16B = 18432 | x [18][2][34]x16B = 19584 }
#define XOFF      18432
#define HALF      38016
#define LDS_BYTES 76032

__device__ __forceinline__ float Gf(int i) {
    return (i < 0 || i > 3) ? 0.f : ((i == 1 || i == 2) ? 3.f : 1.f);
}
__device__ __forceinline__ short f2bf(float f) {
    uint32_t u = __float_as_uint(f);
    u += 0x7fffu + ((u >> 16) & 1u);
    return (short)(u >> 16);
}

// ---------------- fused precompute: prep_e (blocks 0..4607) + xpose (4608..8831)
__global__ __launch_bounds__(256) void prep_kernel(const float* __restrict__ w,
                                                   const float* __restrict__ x,
                                                   short* __restrict__ ews,
                                                   short* __restrict__ xt) {
    __shared__ short tile[64][80];   // used by xpose branch only
    const int t = threadIdx.x;

    if (blockIdx.x < 4608) {
        // ---- E image [tap][hi][oc] per 16-ic phase chunk ----
        int u = blockIdx.x * 256 + t;              // 1,179,648 units of 16B
        int oc_l = u & 31;
        int hi   = (u >> 5) & 1;
        int tap  = (u >> 6) % 18;
        int rest = (u >> 6) / 18;                  // ph + 32*(ocb + 16*pu)
        int ph   = rest & 31;
        int ocb  = (rest >> 5) & 15;
        int pu   = rest >> 9;
        int pv   = tap & 1;
        int ts   = tap >> 1;
        int tt   = ts / 3, ss = ts - tt * 3;
        int m    = 2 * tt + 1 - pu;
        int nn   = 2 * ss + 1 - pv;
        int ic0  = ph * 16 + hi * 8;
        int oc   = ocb * 32 + oc_l;

        v8s o;
        #pragma unroll
        for (int j = 0; j < 8; ++j) {
            float acc = 0.f;
            #pragma unroll
            for (int p = 0; p < 3; ++p) {
                float gm = Gf(m - p);
                if (gm != 0.f) {
                    #pragma unroll
                    for (int q = 0; q < 3; ++q) {
                        float gn = Gf(nn - q);
                        if (gn != 0.f)
                            acc += gm * gn * w[((size_t)(p * 3 + q) * C_IN + ic0 + j) * C_OUT + oc];
                    }
                }
            }
            o[j] = f2bf(acc * COEF);
        }
        *(v8s*)(ews + (size_t)u * 8) = o;
    } else {
        // ---- x -> [n][hp][ph][hi][wp] bf16 via LDS transpose ----
        const int b     = blockIdx.x - 4608;
        const int icb64 = b & 7;
        const int hp    = (b >> 3) % 66;
        const int n     = (b >> 3) / 66;

        const bool hvalid = (hp >= 1 && hp <= 64);
        if (hvalid) {
            #pragma unroll
            for (int r = 0; r < 4; ++r) {
                const int i  = (t >> 4) + r * 16;     // ic_local 0..63
                const int w0 = (t & 15) * 4;          // w 0..63
                const float* src = x + ((size_t)(n * C_IN + icb64 * 64 + i) * HW + (hp - 1)) * HW + w0;
                float4 v = *(const float4*)src;
                tile[w0 + 0][i] = f2bf(v.x);
                tile[w0 + 1][i] = f2bf(v.y);
                tile[w0 + 2][i] = f2bf(v.z);
                tile[w0 + 3][i] = f2bf(v.w);
            }
        }
        __syncthreads();

        // 66 wp x (4 lph x 2 hi) = 528 units of 16B
        for (int u = t; u < 528; u += 256) {
            const int wp  = u >> 3;
            const int gs  = u & 7;
            const int lph = gs >> 1;
            const int hi  = gs & 1;
            v8s o = (v8s)0;
            if (hvalid && wp >= 1 && wp <= 64)
                o = *(const v8s*)&tile[wp - 1][lph * 16 + hi * 8];
            const int ph = icb64 * 4 + hi * 0 + lph;
            *(v8s*)(xt + ((((size_t)(n * 66 + hp) * 32 + ph) * 2 + hi) * 66 + wp) * 8) = o;
        }
    }
}

// ---------------- main MFMA kernel (32x32x16, dbuf, n-per-XCD swizzle) ----------
__global__ __launch_bounds__(256, 2) void conv_mfma_kernel(const short* __restrict__ xt,
                                                           const short* __restrict__ ews,
                                                           float* __restrict__ out) {
    int bid  = blockIdx.x;
    int wgid = (bid & 7) * 256 + (bid >> 3);   // XCD k <=> n = k (2048 blocks, 8 XCDs)
    const int n   = wgid >> 8;
    const int r8  = wgid & 255;
    const int ocb = r8 >> 4;
    const int pu  = (r8 >> 3) & 1;
    const int uhb = (r8 >> 1) & 3;
    const int vhb = r8 & 1;
    const int uh0 = uhb * 16, vh0 = vhb * 32;

    __shared__ char lds_raw[LDS_BYTES];
    AS3 char* lds3 = (AS3 char*)lds_raw;

    const int tid  = threadIdx.x;
    const int lane = tid & 63;
    const int wid  = tid >> 6;      // wave's uh-quarter (0..3)
    const int l31  = lane & 31;
    const int hi   = lane >> 5;

    // E stage source base (chunk for this (pu,ocb), + per-thread 16B unit)
    const short* ebase = ews + (size_t)((pu * 16 + ocb) * 32) * E_PH_SHORTS + (size_t)tid * 8;
    // x stage source base: rows stride 33792 shorts; within phase: hi*528 + wp*8
    const short* xbase = xt + (size_t)(n * 66 + uh0) * 33792 + vh0 * 8;
    // x units: j in [0,1224): j = row*68 + hi*34 + col  (row 0..17, col 0..33)
    int xoff[6], xdst[6];
    #pragma unroll
    for (int k = 0; k < 6; ++k) {
        int j;
        if (k == 0)      j = tid - 128;            // active when tid >= 128
        else if (k == 5) j = 1152 + tid;           // active when tid < 72
        else             j = 128 + (k - 1) * 256 + tid;
        if (j < 0 || j >= 1224) j = 0;
        const int r   = j / 68;
        const int rr  = j - r * 68;
        const int h_  = rr / 34;
        const int c_  = rr - h_ * 34;
        xoff[k] = r * 33792 + h_ * 528 + c_ * 8;
        xdst[k] = XOFF + j * 16;
    }

#define STAGE(bufoff, ph_) do {                                                       \
    const short* ep_ = ebase + (size_t)(ph_) * E_PH_SHORTS;                           \
    const short* xp_ = xbase + (size_t)(ph_) * 1056;                                  \
    _Pragma("unroll")                                                                 \
    for (int it_ = 0; it_ < 4; ++it_)                                                 \
        __builtin_amdgcn_global_load_lds((const AS1 void*)(ep_ + it_ * 2048),         \
            (AS3 void*)(lds3 + (bufoff) + it_ * 4096 + tid * 16), 16, 0, 0);          \
    if (tid < 128)                                                                    \
        __builtin_amdgcn_global_load_lds((const AS1 void*)(ep_ + 8192),               \
            (AS3 void*)(lds3 + (bufoff) + 16384 + tid * 16), 16, 0, 0);               \
    else                                                                              \
        __builtin_amdgcn_global_load_lds((const AS1 void*)(xp_ + xoff[0]),            \
            (AS3 void*)(lds3 + (bufoff) + xdst[0]), 16, 0, 0);                        \
    _Pragma("unroll")                                                                 \
    for (int k_ = 1; k_ < 5; ++k_)                                                    \
        __builtin_amdgcn_global_load_lds((const AS1 void*)(xp_ + xoff[k_]),           \
            (AS3 void*)(lds3 + (bufoff) + xdst[k_]), 16, 0, 0);                       \
    if (tid < 72)                                                                     \
        __builtin_amdgcn_global_load_lds((const AS1 void*)(xp_ + xoff[5]),            \
            (AS3 void*)(lds3 + (bufoff) + xdst[5]), 16, 0, 0);                        \
} while (0)

    v16f acc[4][2];   // [u][pv]
    #pragma unroll
    for (int u = 0; u < 4; ++u)
        #pragma unroll
        for (int pv = 0; pv < 2; ++pv)
            acc[u][pv] = (v16f)0.f;

#define COMPUTE(bufoff) do {                                                          \
    _Pragma("unroll")                                                                 \
    for (int s_ = 0; s_ < 3; ++s_) {                                                  \
        const int c_ = l31 + s_;                                                      \
        v8s A_[6];                                                                    \
        _Pragma("unroll")                                                             \
        for (int rr_ = 0; rr_ < 6; ++rr_)                                             \
            A_[rr_] = *(const v8s*)(lds_raw + (bufoff) + XOFF                         \
                     + (((wid * 4 + rr_) * 2 + hi) * 34 + c_) * 16);                  \
        _Pragma("unroll")                                                             \
        for (int t_ = 0; t_ < 3; ++t_) {                                              \
            _Pragma("unroll")                                                         \
            for (int pv_ = 0; pv_ < 2; ++pv_) {                                       \
                v8s B_ = *(const v8s*)(lds_raw + (bufoff)                             \
                         + ((((t_ * 3 + s_) * 2 + pv_) * 2 + hi) * 32 + l31) * 16);   \
                _Pragma("unroll")                                                     \
                for (int u_ = 0; u_ < 4; ++u_)                                        \
                    acc[u_][pv_] = __builtin_amdgcn_mfma_f32_32x32x16_bf16(           \
                                       A_[u_ + t_], B_, acc[u_][pv_], 0, 0, 0);       \
            }                                                                         \
        }                                                                             \
    }                                                                                 \
} while (0)

    // ---- prologue + double-buffered main loop: one barrier per 16-ic phase ----
    STAGE(0, 0);
    __syncthreads();                       // drain: phase 0 resident
    #pragma unroll 1
    for (int ph = 0; ph < 32; ++ph) {
        const int boff = (ph & 1) ? HALF : 0;
        const int noff = (ph & 1) ? 0 : HALF;
        if (ph < 31) STAGE(noff, ph + 1);  // issue next-phase loads FIRST
        COMPUTE(boff);                     // compute current (hides stage latency)
        __syncthreads();                   // vmcnt(0)+lgkmcnt(0) drain + barrier
    }
#undef STAGE
#undef COMPUTE

    // epilogue: D col = lane&31 (oc), row = (reg&3) + 8*(reg>>2) + 4*(lane>>5) (vh)
    // regs rb..rb+3 are vh-contiguous -> merge into 32B (v8f) stores
    const int oc_g = ocb * 32 + l31;
    float* ob = out + ((size_t)(n * C_OUT + oc_g)) * 128 * 128;
    #pragma unroll
    for (int u = 0; u < 4; ++u) {
        const int h = 2 * (uh0 + wid * 4 + u) + pu;
        #pragma unroll
        for (int g = 0; g < 4; ++g) {
            const int rb    = g * 4;
            const int vh_lb = 8 * g + 4 * hi;
            v8f f;
            #pragma unroll
            for (int i = 0; i < 4; ++i) {
                f[2 * i]     = acc[u][0][rb + i];
                f[2 * i + 1] = acc[u][1][rb + i];
            }
            *(v8f*)(ob + (size_t)h * 128 + 2 * (vh0 + vh_lb)) = f;
        }
    }
}

// ---------------- fallback (validated round-1 VALU kernel) ----------------------
#define ICB 8
#define UB  4
__global__ __launch_bounds__(256) void conv_par_kernel(
        const float* __restrict__ x, const float* __restrict__ w,
        float* __restrict__ out) {
    const int octile = blockIdx.x;
    const int n      = blockIdx.y >> 4;
    const int uhb    = blockIdx.y & 15;
    const int pu     = blockIdx.z >> 1;
    const int pv     = blockIdx.z & 1;
    const int t    = threadIdx.x;
    const int lane = t & 63;
    const int wg   = t >> 6;
    const int ocb  = octile * 64;
    const int uh0  = uhb * UB;
    __shared__ float xs[ICB][6][66];
    __shared__ float esw[9][ICB][64];
    float acc[UB][16];
    #pragma unroll
    for (int u = 0; u < UB; ++u)
        #pragma unroll
        for (int i = 0; i < 16; ++i) acc[u][i] = 0.f;
    for (int icb = 0; icb < C_IN; icb += ICB) {
        __syncthreads();
        for (int e = t; e < ICB * 6 * 66; e += 256) {
            int col = e % 66; int tmp = e / 66; int row = tmp % 6; int ic = tmp / 6;
            int h = uh0 - 1 + row; int ww = col - 1;
            float v = 0.f;
            if (h >= 0 && h < HW && ww >= 0 && ww < HW)
                v = x[((n * C_IN + icb + ic) * HW + h) * HW + ww];
            xs[ic][row][col] = v;
        }
        for (int e = t; e < 9 * ICB * 64; e += 256) {
            int oc = e & 63; int ic = (e >> 6) & (ICB - 1); int pq = e >> 9;
            esw[pq][ic][oc] = w[(pq * C_IN + icb + ic) * C_OUT + ocb + oc];
        }
        __syncthreads();
        float ereg[18];
        #pragma unroll
        for (int j = 0; j < 18; ++j) {
            int e = t + j * 256; int oc = e & 63; int ic = (e >> 6) & (ICB - 1);
            int tap = e >> 9; int t3 = tap / 3, s3 = tap - t3 * 3;
            int m = 2 * t3 + 1 - pu; int nn = 2 * s3 + 1 - pv;
            float gm0 = Gf(m), gm1 = Gf(m - 1), gm2 = Gf(m - 2);
            float gn0 = Gf(nn), gn1 = Gf(nn - 1), gn2 = Gf(nn - 2);
            float s =
              gm0 * (gn0 * esw[0][ic][oc] + gn1 * esw[1][ic][oc] + gn2 * esw[2][ic][oc])
            + gm1 * (gn0 * esw[3][ic][oc] + gn1 * esw[4][ic][oc] + gn2 * esw[5][ic][oc])
            + gm2 * (gn0 * esw[6][ic][oc] + gn1 * esw[7][ic][oc] + gn2 * esw[8][ic][oc]);
            ereg[j] = s * COEF;
        }
        __syncthreads();
        #pragma unroll
        for (int j = 0; j < 18; ++j) {
            int e = t + j * 256; int oc = e & 63; int ic = (e >> 6) & (ICB - 1);
            int tap = e >> 9;
            esw[tap][ic][oc] = ereg[j];
        }
        __syncthreads();
        for (int ic = 0; ic < ICB; ++ic) {
            #pragma unroll
            for (int t3 = 0; t3 < 3; ++t3) {
                #pragma unroll
                for (int s3 = 0; s3 < 3; ++s3) {
                    const int tap = t3 * 3 + s3;
                    float ev[16];
                    #pragma unroll
                    for (int r = 0; r < 4; ++r)
                        *(float4*)&ev[r * 4] = *(const float4*)&esw[tap][ic][wg * 16 + r * 4];
                    float xv[UB];
                    #pragma unroll
                    for (int u = 0; u < UB; ++u) xv[u] = xs[ic][u + t3][lane + s3];
                    #pragma unroll
                    for (int u = 0; u < UB; ++u)
                        #pragma unroll
                        for (int i = 0; i < 16; ++i) acc[u][i] += xv[u] * ev[i];
                }
            }
        }
    }
    #pragma unroll
    for (int u = 0; u < UB; ++u) {
        int urow = 2 * (uh0 + u) + pu;
        #pragma unroll
        for (int i = 0; i < 16; ++i) {
            int oc = ocb + wg * 16 + i;
            out[((n * C_OUT + oc) * 128 + urow) * 128 + 2 * lane + pv] = acc[u][i];
        }
    }
}

extern "C" void kernel_launch(void* const* d_in, const int* in_sizes, int n_in,
                              void* d_out, int out_size, void* d_ws, size_t ws_size,
                              hipStream_t stream) {
    const float* x = (const float*)d_in[0];   // (8,512,64,64) fp32
    const float* w = (const float*)d_in[1];   // (3,3,512,512) fp32 HWIO
    float* out = (float*)d_out;               // (8,512,128,128) fp32

    if (ws_size >= WS_NEED) {
        short* ews = (short*)d_ws;
        short* xtp = (short*)((char*)d_ws + E_WS_BYTES);
        prep_kernel<<<8832, 256, 0, stream>>>(w, x, ews, xtp);
        conv_mfma_kernel<<<2048, 256, 0, stream>>>(xtp, ews, out);
    } else {
        dim3 grid(8, 128, 4);
        conv_par_kernel<<<grid, 256, 0, stream>>>(x, w, out);
    }
}